// Round 4
// baseline (3132.455 us; speedup 1.0000x reference)
//
#include <hip/hip_runtime.h>

typedef __attribute__((ext_vector_type(8))) short short8;
typedef __attribute__((ext_vector_type(4))) float f32x4;
typedef __attribute__((ext_vector_type(4))) unsigned short u16x4;

#define T_SIZE (1u << 22)
#define HMASK 0x3FFFFFu
#define P2H 2654435761u
#define P3H 805459861u
#define NBLK 1024u

__constant__ float c_RES[24] = {
    16.f, 24.f, 36.f, 54.f, 81.f, 121.f, 182.f, 273.f, 410.f, 615.f,
    922.f, 1383.f, 2075.f, 3113.f, 4670.f, 7006.f, 10509.f, 15764.f,
    23646.f, 35469.f, 53204.f, 79806.f, 119709.f, 179563.f};

static __device__ __forceinline__ ushort f2bf(float f) {
    union { float f; unsigned u; } v; v.f = f;
    unsigned r = v.u + 0x7FFFu + ((v.u >> 16) & 1u);
    return (ushort)(r >> 16);
}
static __device__ __forceinline__ float bf2f(ushort u) {
    union { unsigned u; float f; } v; v.u = ((unsigned)u) << 16; return v.f;
}

// Transpose + bf16-convert W1 (96x256) and W2 (256x256) into ws: Wt[n][k].
__global__ void prep_weights(const float* __restrict__ W1, const float* __restrict__ W2,
                             ushort* __restrict__ Wt1, ushort* __restrict__ Wt2) {
    int id = blockIdx.x * 256 + threadIdx.x;
    if (id < 96 * 256) {
        int n = id / 96, k = id - n * 96;
        Wt1[id] = f2bf(W1[k * 256 + n]);
    }
    int id2 = id - 96 * 256;
    if (id2 >= 0 && id2 < 256 * 256) {
        int n = id2 >> 8, k = id2 & 255;
        Wt2[id2] = f2bf(W2[k * 256 + n]);
    }
}

// ---------------- encode, ENFORCED level phasing --------------------------
// 1024 blocks x 256 thr (1 pt/thread), 4 blocks/CU == capacity at <=128 VGPR
// -> all blocks co-resident. Software grid barrier between levels keeps the
// whole GPU gathering from ONE 32MB level table at a time -> table LLC-
// resident -> repeat touches are L3 hits, HBM sees ~32MB/level first-touch.
// Barrier is timeout-protected: a timeout only loses locality, not
// correctness (outputs are barrier-independent).
__global__ __launch_bounds__(256, 4) void encode_phase(
    const float4* __restrict__ coords,
    const float* __restrict__ stab,
    const float* __restrict__ ttab,
    unsigned* __restrict__ feat,
    unsigned* __restrict__ bar) {
    const unsigned p = blockIdx.x * 256u + threadIdx.x;
    const float4 c = coords[p];
    unsigned fs[24], fm[24];

    #pragma unroll
    for (int l = 0; l < 24; ++l) {
        const float R = c_RES[l];
        const unsigned lb = (unsigned)l << 22;

        // spatial
        float sx = c.x * R, sy = c.y * R, sz = c.z * R;
        float bx = floorf(sx), by = floorf(sy), bz = floorf(sz);
        float fx = sx - bx, fy = sy - by, fz = sz - bz;
        unsigned ux = (unsigned)(int)bx, uy = (unsigned)(int)by, uz = (unsigned)(int)bz;
        unsigned hx0 = ux, hx1 = ux + 1u;
        unsigned hy0 = uy * P2H, hy1 = hy0 + P2H;
        unsigned hz0 = uz * P3H, hz1 = hz0 + P3H;
        const float2* st = (const float2*)stab;
        float2 e0 = st[lb + ((hx0 ^ hy0 ^ hz0) & HMASK)];
        float2 e1 = st[lb + ((hx0 ^ hy0 ^ hz1) & HMASK)];
        float2 e2 = st[lb + ((hx0 ^ hy1 ^ hz0) & HMASK)];
        float2 e3 = st[lb + ((hx0 ^ hy1 ^ hz1) & HMASK)];
        float2 e4 = st[lb + ((hx1 ^ hy0 ^ hz0) & HMASK)];
        float2 e5 = st[lb + ((hx1 ^ hy0 ^ hz1) & HMASK)];
        float2 e6 = st[lb + ((hx1 ^ hy1 ^ hz0) & HMASK)];
        float2 e7 = st[lb + ((hx1 ^ hy1 ^ hz1) & HMASK)];
        // temporal
        float stt = c.w * R;
        float bt = floorf(stt);
        float frt = stt - bt;
        unsigned ut = (unsigned)(int)bt;
        const float2* tt = (const float2*)ttab;
        float2 t0 = tt[lb + ((ut * P2H) & HMASK)];
        float2 t1 = tt[lb + (((ut + 1u) * P2H) & HMASK)];

        float wx0 = 1.f - fx, wy0 = 1.f - fy, wz0 = 1.f - fz;
        float f0 = 0.f, f1 = 0.f;
        f0 = fmaf(wx0 * wy0 * wz0, e0.x, f0); f1 = fmaf(wx0 * wy0 * wz0, e0.y, f1);
        f0 = fmaf(wx0 * wy0 * fz,  e1.x, f0); f1 = fmaf(wx0 * wy0 * fz,  e1.y, f1);
        f0 = fmaf(wx0 * fy * wz0,  e2.x, f0); f1 = fmaf(wx0 * fy * wz0,  e2.y, f1);
        f0 = fmaf(wx0 * fy * fz,   e3.x, f0); f1 = fmaf(wx0 * fy * fz,   e3.y, f1);
        f0 = fmaf(fx * wy0 * wz0,  e4.x, f0); f1 = fmaf(fx * wy0 * wz0,  e4.y, f1);
        f0 = fmaf(fx * wy0 * fz,   e5.x, f0); f1 = fmaf(fx * wy0 * fz,   e5.y, f1);
        f0 = fmaf(fx * fy * wz0,   e6.x, f0); f1 = fmaf(fx * fy * wz0,   e6.y, f1);
        f0 = fmaf(fx * fy * fz,    e7.x, f0); f1 = fmaf(fx * fy * fz,    e7.y, f1);
        fs[l] = (unsigned)f2bf(f0) | ((unsigned)f2bf(f1) << 16);

        float g0 = (1.f - frt) * t0.x + frt * t1.x;
        float g1 = (1.f - frt) * t0.y + frt * t1.y;
        fm[l] = (unsigned)f2bf(g0) | ((unsigned)f2bf(g1) << 16);

        // grid-wide level barrier (not after the last level)
        if (l < 23) {
            __syncthreads();
            if (threadIdx.x == 0) {
                __hip_atomic_fetch_add(&bar[l * 8 + (blockIdx.x & 7u)], 1u,
                                       __ATOMIC_RELAXED, __HIP_MEMORY_SCOPE_AGENT);
                for (int spins = 0; spins < 1500; ++spins) {
                    unsigned sum = 0;
                    #pragma unroll
                    for (int i = 0; i < 8; ++i)
                        sum += __hip_atomic_load(&bar[l * 8 + i],
                                                 __ATOMIC_RELAXED, __HIP_MEMORY_SCOPE_AGENT);
                    if (sum >= NBLK) break;
                    __builtin_amdgcn_s_sleep(8);
                }
            }
            __syncthreads();
            asm volatile("" ::: "memory");
        }
    }

    const unsigned sw = (p & 7u) << 2;
    unsigned* row = feat + ((size_t)p << 6);
    #pragma unroll
    for (int g4 = 0; g4 < 6; ++g4) {
        uint4 v; v.x = fs[g4 * 4]; v.y = fs[g4 * 4 + 1];
        v.z = fs[g4 * 4 + 2]; v.w = fs[g4 * 4 + 3];
        *(uint4*)(row + (((unsigned)(g4 * 4)) ^ sw)) = v;
        uint4 w; w.x = fm[g4 * 4]; w.y = fm[g4 * 4 + 1];
        w.z = fm[g4 * 4 + 2]; w.w = fm[g4 * 4 + 3];
        *(uint4*)(row + (((unsigned)(24 + g4 * 4)) ^ sw)) = w;
    }
}

// ---------------- MLP: 64 points/block, swapped-operand MFMA ---------------
__global__ __launch_bounds__(256) void mlp_kernel(
    const unsigned* __restrict__ feat,
    const ushort* __restrict__ Wt1,
    const float* __restrict__ b1,
    const ushort* __restrict__ Wt2,
    const float* __restrict__ b2,
    const float* __restrict__ W3,
    const float* __restrict__ b3,
    float* __restrict__ out) {
    __shared__ __align__(16) ushort feat_lds[64 * 128];  // 16KB, swizzled rows
    __shared__ __align__(16) ushort h_lds[64 * 264];     // 33792B
    __shared__ float w3_lds[772];

    const int tid = threadIdx.x;
    const int lane = tid & 63, wv = tid >> 6;
    const int lr = lane & 15, chunk = lane >> 4;
    const int nb = wv * 64;

    for (int i = tid; i < 768; i += 256) w3_lds[i] = W3[i];
    if (tid < 3) w3_lds[768 + tid] = b3[tid];

    {
        const char* g = (const char*)(feat + (size_t)blockIdx.x * 4096) + wv * 4096 + lane * 16;
        #pragma unroll
        for (int it = 0; it < 4; ++it)
            __builtin_amdgcn_global_load_lds(
                (const __attribute__((address_space(1))) unsigned*)(g + it * 1024),
                (__attribute__((address_space(3))) unsigned*)&feat_lds[wv * 2048 + it * 512],
                16, 0, 0);
    }
    __syncthreads();

    // ----- layer 1: K=96
    f32x4 acc[4][4] = {};
    #pragma unroll
    for (int ks = 0; ks < 3; ++ks) {
        short8 a[4], b[4];
        #pragma unroll
        for (int ni = 0; ni < 4; ++ni)
            a[ni] = *(const short8*)&Wt1[(size_t)(nb + ni * 16 + lr) * 96 + ks * 32 + chunk * 8];
        #pragma unroll
        for (int mi = 0; mi < 4; ++mi) {
            int m = mi * 16 + lr;
            int w = (ks * 16 + chunk * 4) ^ ((m & 7) << 2);
            b[mi] = *(const short8*)&feat_lds[m * 128 + 2 * w];
        }
        #pragma unroll
        for (int ni = 0; ni < 4; ++ni)
            #pragma unroll
            for (int mi = 0; mi < 4; ++mi)
                acc[ni][mi] = __builtin_amdgcn_mfma_f32_16x16x32_bf16(a[ni], b[mi], acc[ni][mi], 0, 0, 0);
    }
    #pragma unroll
    for (int ni = 0; ni < 4; ++ni) {
        float4 bn = *(const float4*)&b1[nb + ni * 16 + chunk * 4];
        #pragma unroll
        for (int mi = 0; mi < 4; ++mi) {
            u16x4 v;
            v.x = f2bf(fmaxf(acc[ni][mi][0] + bn.x, 0.f));
            v.y = f2bf(fmaxf(acc[ni][mi][1] + bn.y, 0.f));
            v.z = f2bf(fmaxf(acc[ni][mi][2] + bn.z, 0.f));
            v.w = f2bf(fmaxf(acc[ni][mi][3] + bn.w, 0.f));
            *(u16x4*)&h_lds[(mi * 16 + lr) * 264 + nb + ni * 16 + chunk * 4] = v;
        }
    }
    __syncthreads();

    // ----- layer 2: K=256
    f32x4 acc2[4][4] = {};
    #pragma unroll
    for (int ks = 0; ks < 8; ++ks) {
        short8 a[4], b[4];
        #pragma unroll
        for (int ni = 0; ni < 4; ++ni)
            a[ni] = *(const short8*)&Wt2[(size_t)(nb + ni * 16 + lr) * 256 + ks * 32 + chunk * 8];
        #pragma unroll
        for (int mi = 0; mi < 4; ++mi)
            b[mi] = *(const short8*)&h_lds[(mi * 16 + lr) * 264 + ks * 32 + chunk * 8];
        #pragma unroll
        for (int ni = 0; ni < 4; ++ni)
            #pragma unroll
            for (int mi = 0; mi < 4; ++mi)
                acc2[ni][mi] = __builtin_amdgcn_mfma_f32_16x16x32_bf16(a[ni], b[mi], acc2[ni][mi], 0, 0, 0);
    }
    __syncthreads();
    #pragma unroll
    for (int ni = 0; ni < 4; ++ni) {
        float4 bn = *(const float4*)&b2[nb + ni * 16 + chunk * 4];
        #pragma unroll
        for (int mi = 0; mi < 4; ++mi) {
            u16x4 v;
            v.x = f2bf(fmaxf(acc2[ni][mi][0] + bn.x, 0.f));
            v.y = f2bf(fmaxf(acc2[ni][mi][1] + bn.y, 0.f));
            v.z = f2bf(fmaxf(acc2[ni][mi][2] + bn.z, 0.f));
            v.w = f2bf(fmaxf(acc2[ni][mi][3] + bn.w, 0.f));
            *(u16x4*)&h_lds[(mi * 16 + lr) * 264 + nb + ni * 16 + chunk * 4] = v;
        }
    }
    __syncthreads();

    // ----- layer 3 + sigmoid
    if (tid < 192) {
        const int pp = tid / 3;
        const int cc = tid - 3 * pp;
        float s = w3_lds[768 + cc];
        #pragma unroll 8
        for (int k = 0; k < 256; ++k)
            s = fmaf(bf2f(h_lds[pp * 264 + k]), w3_lds[k * 3 + cc], s);
        out[(size_t)(blockIdx.x * 64 + pp) * 3 + cc] = 1.f / (1.f + expf(-s));
    }
}

// ---------------- fallback (R1 fused kernel) if ws too small ---------------
#define FLD 104
#define HLD 264
__global__ __launch_bounds__(256) void fused_ngp_fb(
    const float4* __restrict__ coords, const float* __restrict__ stab,
    const float* __restrict__ ttab, const ushort* __restrict__ Wt1,
    const float* __restrict__ b1, const ushort* __restrict__ Wt2,
    const float* __restrict__ b2, const float* __restrict__ W3,
    const float* __restrict__ b3, float* __restrict__ out) {
    __shared__ ushort feat_lds[64 * FLD];
    __shared__ ushort h_lds[64 * HLD];
    __shared__ float w3_lds[772];
    const int tid = threadIdx.x;
    for (int i = tid; i < 768; i += 256) w3_lds[i] = W3[i];
    if (tid < 3) w3_lds[768 + tid] = b3[tid];
    const int p = tid & 63;
    const int g = tid >> 6;
    const float4 c = coords[blockIdx.x * 64 + p];
    #pragma unroll
    for (int dl = 0; dl < 6; ++dl) {
        const int l = g * 6 + dl;
        const float R = c_RES[l];
        float sx = c.x * R, sy = c.y * R, sz = c.z * R;
        float bx = floorf(sx), by = floorf(sy), bz = floorf(sz);
        float fx = sx - bx, fy = sy - by, fz = sz - bz;
        unsigned ux = (unsigned)(int)bx, uy = (unsigned)(int)by, uz = (unsigned)(int)bz;
        unsigned hx0 = ux, hx1 = ux + 1u;
        unsigned hy0 = uy * P2H, hy1 = hy0 + P2H;
        unsigned hz0 = uz * P3H, hz1 = hz0 + P3H;
        const float2* tl = (const float2*)stab + (size_t)l * T_SIZE;
        unsigned h[8];
        h[0] = (hx0 ^ hy0 ^ hz0) & HMASK; h[1] = (hx0 ^ hy0 ^ hz1) & HMASK;
        h[2] = (hx0 ^ hy1 ^ hz0) & HMASK; h[3] = (hx0 ^ hy1 ^ hz1) & HMASK;
        h[4] = (hx1 ^ hy0 ^ hz0) & HMASK; h[5] = (hx1 ^ hy0 ^ hz1) & HMASK;
        h[6] = (hx1 ^ hy1 ^ hz0) & HMASK; h[7] = (hx1 ^ hy1 ^ hz1) & HMASK;
        float2 e[8];
        #pragma unroll
        for (int q = 0; q < 8; ++q) e[q] = tl[h[q]];
        float wx0 = 1.f - fx, wy0 = 1.f - fy, wz0 = 1.f - fz;
        float w[8] = {wx0 * wy0 * wz0, wx0 * wy0 * fz, wx0 * fy * wz0, wx0 * fy * fz,
                      fx * wy0 * wz0,  fx * wy0 * fz,  fx * fy * wz0,  fx * fy * fz};
        float f0 = 0.f, f1 = 0.f;
        #pragma unroll
        for (int q = 0; q < 8; ++q) { f0 = fmaf(w[q], e[q].x, f0); f1 = fmaf(w[q], e[q].y, f1); }
        feat_lds[p * FLD + 2 * l] = f2bf(f0);
        feat_lds[p * FLD + 2 * l + 1] = f2bf(f1);
        float stv = c.w * R;
        float btf = floorf(stv);
        float ftv = stv - btf;
        unsigned utv = (unsigned)(int)btf;
        const float2* ttl = (const float2*)ttab + (size_t)l * T_SIZE;
        float2 e0 = ttl[(utv * P2H) & HMASK], e1 = ttl[((utv + 1u) * P2H) & HMASK];
        feat_lds[p * FLD + 48 + 2 * l] = f2bf((1.f - ftv) * e0.x + ftv * e1.x);
        feat_lds[p * FLD + 48 + 2 * l + 1] = f2bf((1.f - ftv) * e0.y + ftv * e1.y);
    }
    __syncthreads();
    const int lane = tid & 63;
    const int wv = tid >> 6;
    const int lr = lane & 15;
    const int lk = (lane >> 4) * 8;
    const int nb = wv * 64;
    const int rbase = (lane >> 4) * 4;
    f32x4 acc[4][4] = {};
    #pragma unroll
    for (int ks = 0; ks < 3; ++ks) {
        short8 a[4], b[4];
        #pragma unroll
        for (int mi = 0; mi < 4; ++mi)
            a[mi] = *(const short8*)&feat_lds[(mi * 16 + lr) * FLD + ks * 32 + lk];
        #pragma unroll
        for (int ni = 0; ni < 4; ++ni)
            b[ni] = *(const short8*)&Wt1[(size_t)(nb + ni * 16 + lr) * 96 + ks * 32 + lk];
        #pragma unroll
        for (int mi = 0; mi < 4; ++mi)
            #pragma unroll
            for (int ni = 0; ni < 4; ++ni)
                acc[mi][ni] = __builtin_amdgcn_mfma_f32_16x16x32_bf16(a[mi], b[ni], acc[mi][ni], 0, 0, 0);
    }
    {
        float bn[4];
        #pragma unroll
        for (int ni = 0; ni < 4; ++ni) bn[ni] = b1[nb + ni * 16 + lr];
        #pragma unroll
        for (int mi = 0; mi < 4; ++mi)
            #pragma unroll
            for (int ni = 0; ni < 4; ++ni)
                #pragma unroll
                for (int r = 0; r < 4; ++r)
                    h_lds[(mi * 16 + rbase + r) * HLD + nb + ni * 16 + lr] =
                        f2bf(fmaxf(acc[mi][ni][r] + bn[ni], 0.f));
    }
    __syncthreads();
    f32x4 acc2[4][4] = {};
    #pragma unroll
    for (int ks = 0; ks < 8; ++ks) {
        short8 a[4], b[4];
        #pragma unroll
        for (int mi = 0; mi < 4; ++mi)
            a[mi] = *(const short8*)&h_lds[(mi * 16 + lr) * HLD + ks * 32 + lk];
        #pragma unroll
        for (int ni = 0; ni < 4; ++ni)
            b[ni] = *(const short8*)&Wt2[(size_t)(nb + ni * 16 + lr) * 256 + ks * 32 + lk];
        #pragma unroll
        for (int mi = 0; mi < 4; ++mi)
            #pragma unroll
            for (int ni = 0; ni < 4; ++ni)
                acc2[mi][ni] = __builtin_amdgcn_mfma_f32_16x16x32_bf16(a[mi], b[ni], acc2[mi][ni], 0, 0, 0);
    }
    __syncthreads();
    {
        float bn2[4];
        #pragma unroll
        for (int ni = 0; ni < 4; ++ni) bn2[ni] = b2[nb + ni * 16 + lr];
        #pragma unroll
        for (int mi = 0; mi < 4; ++mi)
            #pragma unroll
            for (int ni = 0; ni < 4; ++ni)
                #pragma unroll
                for (int r = 0; r < 4; ++r)
                    h_lds[(mi * 16 + rbase + r) * HLD + nb + ni * 16 + lr] =
                        f2bf(fmaxf(acc2[mi][ni][r] + bn2[ni], 0.f));
    }
    __syncthreads();
    if (tid < 192) {
        const int pp = tid / 3;
        const int cc = tid - 3 * pp;
        float s = w3_lds[768 + cc];
        #pragma unroll 8
        for (int k = 0; k < 256; ++k)
            s = fmaf(bf2f(h_lds[pp * HLD + k]), w3_lds[k * 3 + cc], s);
        out[(size_t)(blockIdx.x * 64 + pp) * 3 + cc] = 1.f / (1.f + expf(-s));
    }
}

extern "C" void kernel_launch(void* const* d_in, const int* in_sizes, int n_in,
                              void* d_out, int out_size, void* d_ws, size_t ws_size,
                              hipStream_t stream) {
    const float* coords = (const float*)d_in[0];
    const float* stab   = (const float*)d_in[1];
    const float* ttab   = (const float*)d_in[2];
    const float* W1     = (const float*)d_in[3];
    const float* b1     = (const float*)d_in[4];
    const float* W2     = (const float*)d_in[5];
    const float* b2     = (const float*)d_in[6];
    const float* W3     = (const float*)d_in[7];
    const float* b3     = (const float*)d_in[8];

    const int B = in_sizes[0] / 4;  // 262144
    const size_t FEAT_BYTES = (size_t)B * 256;             // bf16 [B][128]
    const size_t W_BYTES = (96 * 256 + 256 * 256) * 2;     // 180224
    const size_t BAR_BYTES = 24 * 8 * sizeof(unsigned);    // 768

    if (ws_size >= FEAT_BYTES + W_BYTES + BAR_BYTES) {
        unsigned* feat = (unsigned*)d_ws;                  // [B][64] words
        ushort* Wt1 = (ushort*)((char*)d_ws + FEAT_BYTES);
        ushort* Wt2 = Wt1 + 96 * 256;
        unsigned* bar = (unsigned*)((char*)d_ws + FEAT_BYTES + W_BYTES);

        hipMemsetAsync(bar, 0, BAR_BYTES, stream);
        prep_weights<<<352, 256, 0, stream>>>(W1, W2, Wt1, Wt2);
        encode_phase<<<NBLK, 256, 0, stream>>>(
            (const float4*)coords, stab, ttab, feat, bar);
        mlp_kernel<<<B / 64, 256, 0, stream>>>(feat, Wt1, b1, Wt2, b2, W3, b3,
                                               (float*)d_out);
    } else {
        ushort* Wt1 = (ushort*)d_ws;
        ushort* Wt2 = Wt1 + 96 * 256;
        prep_weights<<<352, 256, 0, stream>>>(W1, W2, Wt1, Wt2);
        fused_ngp_fb<<<B / 64, 256, 0, stream>>>((const float4*)coords, stab, ttab,
                                                 Wt1, b1, Wt2, b2, W3, b3,
                                                 (float*)d_out);
    }
}

// Round 5
// 1305.482 us; speedup vs baseline: 2.3995x; 2.3995x over previous
//
#include <hip/hip_runtime.h>

typedef __attribute__((ext_vector_type(8))) short short8;
typedef __attribute__((ext_vector_type(4))) float f32x4;
typedef __attribute__((ext_vector_type(4))) unsigned short u16x4;

#define T_SIZE (1u << 22)
#define HMASK 0x3FFFFFu
#define P2H 2654435761u
#define P3H 805459861u
#define NBLK 1024u

__constant__ float c_RES[24] = {
    16.f, 24.f, 36.f, 54.f, 81.f, 121.f, 182.f, 273.f, 410.f, 615.f,
    922.f, 1383.f, 2075.f, 3113.f, 4670.f, 7006.f, 10509.f, 15764.f,
    23646.f, 35469.f, 53204.f, 79806.f, 119709.f, 179563.f};

static __device__ __forceinline__ ushort f2bf(float f) {
    union { float f; unsigned u; } v; v.f = f;
    unsigned r = v.u + 0x7FFFu + ((v.u >> 16) & 1u);
    return (ushort)(r >> 16);
}
static __device__ __forceinline__ float bf2f(ushort u) {
    union { unsigned u; float f; } v; v.u = ((unsigned)u) << 16; return v.f;
}

// Transpose + bf16-convert W1 (96x256) and W2 (256x256) into ws: Wt[n][k].
__global__ void prep_weights(const float* __restrict__ W1, const float* __restrict__ W2,
                             ushort* __restrict__ Wt1, ushort* __restrict__ Wt2) {
    int id = blockIdx.x * 256 + threadIdx.x;
    if (id < 96 * 256) {
        int n = id / 96, k = id - n * 96;
        Wt1[id] = f2bf(W1[k * 256 + n]);
    }
    int id2 = id - 96 * 256;
    if (id2 >= 0 && id2 < 256 * 256) {
        int n = id2 >> 8, k = id2 & 255;
        Wt2[id2] = f2bf(W2[k * 256 + n]);
    }
}

// one level's spatial+temporal features (l is compile-time-constant at call
// sites inside unrolled loops -> everything folds, no arrays, no spills)
static __device__ __forceinline__ void enc_level(
    int l, const float4 c, const float2* __restrict__ st,
    const float2* __restrict__ tt, unsigned& outs, unsigned& outt) {
    const float R = c_RES[l];
    const unsigned lb = (unsigned)l << 22;

    float sx = c.x * R, sy = c.y * R, sz = c.z * R;
    float bx = floorf(sx), by = floorf(sy), bz = floorf(sz);
    float fx = sx - bx, fy = sy - by, fz = sz - bz;
    unsigned ux = (unsigned)(int)bx, uy = (unsigned)(int)by, uz = (unsigned)(int)bz;
    unsigned hx0 = ux, hx1 = ux + 1u;
    unsigned hy0 = uy * P2H, hy1 = hy0 + P2H;
    unsigned hz0 = uz * P3H, hz1 = hz0 + P3H;
    float2 e0 = st[lb + ((hx0 ^ hy0 ^ hz0) & HMASK)];
    float2 e1 = st[lb + ((hx0 ^ hy0 ^ hz1) & HMASK)];
    float2 e2 = st[lb + ((hx0 ^ hy1 ^ hz0) & HMASK)];
    float2 e3 = st[lb + ((hx0 ^ hy1 ^ hz1) & HMASK)];
    float2 e4 = st[lb + ((hx1 ^ hy0 ^ hz0) & HMASK)];
    float2 e5 = st[lb + ((hx1 ^ hy0 ^ hz1) & HMASK)];
    float2 e6 = st[lb + ((hx1 ^ hy1 ^ hz0) & HMASK)];
    float2 e7 = st[lb + ((hx1 ^ hy1 ^ hz1) & HMASK)];

    float stt = c.w * R;
    float bt = floorf(stt);
    float frt = stt - bt;
    unsigned ut = (unsigned)(int)bt;
    float2 t0 = tt[lb + ((ut * P2H) & HMASK)];
    float2 t1 = tt[lb + (((ut + 1u) * P2H) & HMASK)];

    float wx0 = 1.f - fx, wy0 = 1.f - fy, wz0 = 1.f - fz;
    float f0 = 0.f, f1 = 0.f;
    f0 = fmaf(wx0 * wy0 * wz0, e0.x, f0); f1 = fmaf(wx0 * wy0 * wz0, e0.y, f1);
    f0 = fmaf(wx0 * wy0 * fz,  e1.x, f0); f1 = fmaf(wx0 * wy0 * fz,  e1.y, f1);
    f0 = fmaf(wx0 * fy * wz0,  e2.x, f0); f1 = fmaf(wx0 * fy * wz0,  e2.y, f1);
    f0 = fmaf(wx0 * fy * fz,   e3.x, f0); f1 = fmaf(wx0 * fy * fz,   e3.y, f1);
    f0 = fmaf(fx * wy0 * wz0,  e4.x, f0); f1 = fmaf(fx * wy0 * wz0,  e4.y, f1);
    f0 = fmaf(fx * wy0 * fz,   e5.x, f0); f1 = fmaf(fx * wy0 * fz,   e5.y, f1);
    f0 = fmaf(fx * fy * wz0,   e6.x, f0); f1 = fmaf(fx * fy * wz0,   e6.y, f1);
    f0 = fmaf(fx * fy * fz,    e7.x, f0); f1 = fmaf(fx * fy * fz,    e7.y, f1);
    outs = (unsigned)f2bf(f0) | ((unsigned)f2bf(f1) << 16);

    float g0 = (1.f - frt) * t0.x + frt * t1.x;
    float g1 = (1.f - frt) * t0.y + frt * t1.y;
    outt = (unsigned)f2bf(g0) | ((unsigned)f2bf(g1) << 16);
}

// grid barrier: leader adds to 1 of 8 striped counters; lanes 0..7 of wave 0
// each poll one counter until it reaches NBLK/8. Timeout-protected (a timeout
// only loses cache locality, never correctness).
static __device__ __forceinline__ void grid_barrier(unsigned* __restrict__ bar,
                                                    int phase) {
    __syncthreads();
    if (threadIdx.x == 0)
        __hip_atomic_fetch_add(&bar[phase * 8 + (blockIdx.x & 7u)], 1u,
                               __ATOMIC_RELAXED, __HIP_MEMORY_SCOPE_AGENT);
    if (threadIdx.x < 8) {
        const unsigned* ctr = &bar[phase * 8 + threadIdx.x];
        for (int spins = 0; spins < 2000; ++spins) {
            if (__hip_atomic_load(ctr, __ATOMIC_RELAXED,
                                  __HIP_MEMORY_SCOPE_AGENT) >= NBLK / 8u) break;
            __builtin_amdgcn_s_sleep(4);
        }
    }
    __syncthreads();
    asm volatile("" ::: "memory");
}

// ---------------- encode, ENFORCED level phasing, spill-free ---------------
// 1024 blocks x 256 thr (1 pt/thread), 4 blocks/CU == exactly co-resident.
// 6 phases x 4 levels; grid barrier between phases. During a phase the live
// table footprint (4 spatial tables = 128MB + sparse temporal) fits the
// 256MB Infinity Cache -> repeat touches served by LLC instead of HBM.
// Each phase writes its two aligned uint4 feat groups immediately -> no
// cross-phase register arrays -> no scratch spills.
__global__ __launch_bounds__(256, 4) void encode_phase(
    const float4* __restrict__ coords,
    const float* __restrict__ stab,
    const float* __restrict__ ttab,
    unsigned* __restrict__ feat,
    unsigned* __restrict__ bar) {
    const unsigned p = blockIdx.x * 256u + threadIdx.x;
    const float4 c = coords[p];
    const float2* st = (const float2*)stab;
    const float2* tt = (const float2*)ttab;
    const unsigned sw = (p & 7u) << 2;
    unsigned* row = feat + ((size_t)p << 6);

    #pragma unroll
    for (int g4 = 0; g4 < 6; ++g4) {
        uint4 vs, vt;
        enc_level(g4 * 4 + 0, c, st, tt, vs.x, vt.x);
        enc_level(g4 * 4 + 1, c, st, tt, vs.y, vt.y);
        enc_level(g4 * 4 + 2, c, st, tt, vs.z, vt.z);
        enc_level(g4 * 4 + 3, c, st, tt, vs.w, vt.w);
        *(uint4*)(row + (((unsigned)(g4 * 4)) ^ sw)) = vs;
        *(uint4*)(row + (((unsigned)(24 + g4 * 4)) ^ sw)) = vt;
        if (g4 < 5) grid_barrier(bar, g4);
    }
}

// ---------------- MLP: 64 points/block, swapped-operand MFMA ---------------
__global__ __launch_bounds__(256) void mlp_kernel(
    const unsigned* __restrict__ feat,
    const ushort* __restrict__ Wt1,
    const float* __restrict__ b1,
    const ushort* __restrict__ Wt2,
    const float* __restrict__ b2,
    const float* __restrict__ W3,
    const float* __restrict__ b3,
    float* __restrict__ out) {
    __shared__ __align__(16) ushort feat_lds[64 * 128];  // 16KB, swizzled rows
    __shared__ __align__(16) ushort h_lds[64 * 264];     // 33792B
    __shared__ float w3_lds[772];

    const int tid = threadIdx.x;
    const int lane = tid & 63, wv = tid >> 6;
    const int lr = lane & 15, chunk = lane >> 4;
    const int nb = wv * 64;

    for (int i = tid; i < 768; i += 256) w3_lds[i] = W3[i];
    if (tid < 3) w3_lds[768 + tid] = b3[tid];

    {
        const char* g = (const char*)(feat + (size_t)blockIdx.x * 4096) + wv * 4096 + lane * 16;
        #pragma unroll
        for (int it = 0; it < 4; ++it)
            __builtin_amdgcn_global_load_lds(
                (const __attribute__((address_space(1))) unsigned*)(g + it * 1024),
                (__attribute__((address_space(3))) unsigned*)&feat_lds[wv * 2048 + it * 512],
                16, 0, 0);
    }
    __syncthreads();

    // ----- layer 1: K=96
    f32x4 acc[4][4] = {};
    #pragma unroll
    for (int ks = 0; ks < 3; ++ks) {
        short8 a[4], b[4];
        #pragma unroll
        for (int ni = 0; ni < 4; ++ni)
            a[ni] = *(const short8*)&Wt1[(size_t)(nb + ni * 16 + lr) * 96 + ks * 32 + chunk * 8];
        #pragma unroll
        for (int mi = 0; mi < 4; ++mi) {
            int m = mi * 16 + lr;
            int w = (ks * 16 + chunk * 4) ^ ((m & 7) << 2);
            b[mi] = *(const short8*)&feat_lds[m * 128 + 2 * w];
        }
        #pragma unroll
        for (int ni = 0; ni < 4; ++ni)
            #pragma unroll
            for (int mi = 0; mi < 4; ++mi)
                acc[ni][mi] = __builtin_amdgcn_mfma_f32_16x16x32_bf16(a[ni], b[mi], acc[ni][mi], 0, 0, 0);
    }
    #pragma unroll
    for (int ni = 0; ni < 4; ++ni) {
        float4 bn = *(const float4*)&b1[nb + ni * 16 + chunk * 4];
        #pragma unroll
        for (int mi = 0; mi < 4; ++mi) {
            u16x4 v;
            v.x = f2bf(fmaxf(acc[ni][mi][0] + bn.x, 0.f));
            v.y = f2bf(fmaxf(acc[ni][mi][1] + bn.y, 0.f));
            v.z = f2bf(fmaxf(acc[ni][mi][2] + bn.z, 0.f));
            v.w = f2bf(fmaxf(acc[ni][mi][3] + bn.w, 0.f));
            *(u16x4*)&h_lds[(mi * 16 + lr) * 264 + nb + ni * 16 + chunk * 4] = v;
        }
    }
    __syncthreads();

    // ----- layer 2: K=256
    f32x4 acc2[4][4] = {};
    #pragma unroll
    for (int ks = 0; ks < 8; ++ks) {
        short8 a[4], b[4];
        #pragma unroll
        for (int ni = 0; ni < 4; ++ni)
            a[ni] = *(const short8*)&Wt2[(size_t)(nb + ni * 16 + lr) * 256 + ks * 32 + chunk * 8];
        #pragma unroll
        for (int mi = 0; mi < 4; ++mi)
            b[mi] = *(const short8*)&h_lds[(mi * 16 + lr) * 264 + ks * 32 + chunk * 8];
        #pragma unroll
        for (int ni = 0; ni < 4; ++ni)
            #pragma unroll
            for (int mi = 0; mi < 4; ++mi)
                acc2[ni][mi] = __builtin_amdgcn_mfma_f32_16x16x32_bf16(a[ni], b[mi], acc2[ni][mi], 0, 0, 0);
    }
    __syncthreads();
    #pragma unroll
    for (int ni = 0; ni < 4; ++ni) {
        float4 bn = *(const float4*)&b2[nb + ni * 16 + chunk * 4];
        #pragma unroll
        for (int mi = 0; mi < 4; ++mi) {
            u16x4 v;
            v.x = f2bf(fmaxf(acc2[ni][mi][0] + bn.x, 0.f));
            v.y = f2bf(fmaxf(acc2[ni][mi][1] + bn.y, 0.f));
            v.z = f2bf(fmaxf(acc2[ni][mi][2] + bn.z, 0.f));
            v.w = f2bf(fmaxf(acc2[ni][mi][3] + bn.w, 0.f));
            *(u16x4*)&h_lds[(mi * 16 + lr) * 264 + nb + ni * 16 + chunk * 4] = v;
        }
    }
    __syncthreads();

    // ----- layer 3 + sigmoid
    if (tid < 192) {
        const int pp = tid / 3;
        const int cc = tid - 3 * pp;
        float s = w3_lds[768 + cc];
        #pragma unroll 8
        for (int k = 0; k < 256; ++k)
            s = fmaf(bf2f(h_lds[pp * 264 + k]), w3_lds[k * 3 + cc], s);
        out[(size_t)(blockIdx.x * 64 + pp) * 3 + cc] = 1.f / (1.f + expf(-s));
    }
}

// ---------------- fallback (R1 fused kernel) if ws too small ---------------
#define FLD 104
#define HLD 264
__global__ __launch_bounds__(256) void fused_ngp_fb(
    const float4* __restrict__ coords, const float* __restrict__ stab,
    const float* __restrict__ ttab, const ushort* __restrict__ Wt1,
    const float* __restrict__ b1, const ushort* __restrict__ Wt2,
    const float* __restrict__ b2, const float* __restrict__ W3,
    const float* __restrict__ b3, float* __restrict__ out) {
    __shared__ ushort feat_lds[64 * FLD];
    __shared__ ushort h_lds[64 * HLD];
    __shared__ float w3_lds[772];
    const int tid = threadIdx.x;
    for (int i = tid; i < 768; i += 256) w3_lds[i] = W3[i];
    if (tid < 3) w3_lds[768 + tid] = b3[tid];
    const int p = tid & 63;
    const int g = tid >> 6;
    const float4 c = coords[blockIdx.x * 64 + p];
    #pragma unroll
    for (int dl = 0; dl < 6; ++dl) {
        const int l = g * 6 + dl;
        const float R = c_RES[l];
        float sx = c.x * R, sy = c.y * R, sz = c.z * R;
        float bx = floorf(sx), by = floorf(sy), bz = floorf(sz);
        float fx = sx - bx, fy = sy - by, fz = sz - bz;
        unsigned ux = (unsigned)(int)bx, uy = (unsigned)(int)by, uz = (unsigned)(int)bz;
        unsigned hx0 = ux, hx1 = ux + 1u;
        unsigned hy0 = uy * P2H, hy1 = hy0 + P2H;
        unsigned hz0 = uz * P3H, hz1 = hz0 + P3H;
        const float2* tl = (const float2*)stab + (size_t)l * T_SIZE;
        unsigned h[8];
        h[0] = (hx0 ^ hy0 ^ hz0) & HMASK; h[1] = (hx0 ^ hy0 ^ hz1) & HMASK;
        h[2] = (hx0 ^ hy1 ^ hz0) & HMASK; h[3] = (hx0 ^ hy1 ^ hz1) & HMASK;
        h[4] = (hx1 ^ hy0 ^ hz0) & HMASK; h[5] = (hx1 ^ hy0 ^ hz1) & HMASK;
        h[6] = (hx1 ^ hy1 ^ hz0) & HMASK; h[7] = (hx1 ^ hy1 ^ hz1) & HMASK;
        float2 e[8];
        #pragma unroll
        for (int q = 0; q < 8; ++q) e[q] = tl[h[q]];
        float wx0 = 1.f - fx, wy0 = 1.f - fy, wz0 = 1.f - fz;
        float w[8] = {wx0 * wy0 * wz0, wx0 * wy0 * fz, wx0 * fy * wz0, wx0 * fy * fz,
                      fx * wy0 * wz0,  fx * wy0 * fz,  fx * fy * wz0,  fx * fy * fz};
        float f0 = 0.f, f1 = 0.f;
        #pragma unroll
        for (int q = 0; q < 8; ++q) { f0 = fmaf(w[q], e[q].x, f0); f1 = fmaf(w[q], e[q].y, f1); }
        feat_lds[p * FLD + 2 * l] = f2bf(f0);
        feat_lds[p * FLD + 2 * l + 1] = f2bf(f1);
        float stv = c.w * R;
        float btf = floorf(stv);
        float ftv = stv - btf;
        unsigned utv = (unsigned)(int)btf;
        const float2* ttl = (const float2*)ttab + (size_t)l * T_SIZE;
        float2 e0 = ttl[(utv * P2H) & HMASK], e1 = ttl[((utv + 1u) * P2H) & HMASK];
        feat_lds[p * FLD + 48 + 2 * l] = f2bf((1.f - ftv) * e0.x + ftv * e1.x);
        feat_lds[p * FLD + 48 + 2 * l + 1] = f2bf((1.f - ftv) * e0.y + ftv * e1.y);
    }
    __syncthreads();
    const int lane = tid & 63;
    const int wv = tid >> 6;
    const int lr = lane & 15;
    const int lk = (lane >> 4) * 8;
    const int nb = wv * 64;
    const int rbase = (lane >> 4) * 4;
    f32x4 acc[4][4] = {};
    #pragma unroll
    for (int ks = 0; ks < 3; ++ks) {
        short8 a[4], b[4];
        #pragma unroll
        for (int mi = 0; mi < 4; ++mi)
            a[mi] = *(const short8*)&feat_lds[(mi * 16 + lr) * FLD + ks * 32 + lk];
        #pragma unroll
        for (int ni = 0; ni < 4; ++ni)
            b[ni] = *(const short8*)&Wt1[(size_t)(nb + ni * 16 + lr) * 96 + ks * 32 + lk];
        #pragma unroll
        for (int mi = 0; mi < 4; ++mi)
            #pragma unroll
            for (int ni = 0; ni < 4; ++ni)
                acc[mi][ni] = __builtin_amdgcn_mfma_f32_16x16x32_bf16(a[mi], b[ni], acc[mi][ni], 0, 0, 0);
    }
    {
        float bn[4];
        #pragma unroll
        for (int ni = 0; ni < 4; ++ni) bn[ni] = b1[nb + ni * 16 + lr];
        #pragma unroll
        for (int mi = 0; mi < 4; ++mi)
            #pragma unroll
            for (int ni = 0; ni < 4; ++ni)
                #pragma unroll
                for (int r = 0; r < 4; ++r)
                    h_lds[(mi * 16 + rbase + r) * HLD + nb + ni * 16 + lr] =
                        f2bf(fmaxf(acc[mi][ni][r] + bn[ni], 0.f));
    }
    __syncthreads();
    f32x4 acc2[4][4] = {};
    #pragma unroll
    for (int ks = 0; ks < 8; ++ks) {
        short8 a[4], b[4];
        #pragma unroll
        for (int mi = 0; mi < 4; ++mi)
            a[mi] = *(const short8*)&h_lds[(mi * 16 + lr) * HLD + ks * 32 + lk];
        #pragma unroll
        for (int ni = 0; ni < 4; ++ni)
            b[ni] = *(const short8*)&Wt2[(size_t)(nb + ni * 16 + lr) * 256 + ks * 32 + lk];
        #pragma unroll
        for (int mi = 0; mi < 4; ++mi)
            #pragma unroll
            for (int ni = 0; ni < 4; ++ni)
                acc2[mi][ni] = __builtin_amdgcn_mfma_f32_16x16x32_bf16(a[mi], b[ni], acc2[mi][ni], 0, 0, 0);
    }
    __syncthreads();
    {
        float bn2[4];
        #pragma unroll
        for (int ni = 0; ni < 4; ++ni) bn2[ni] = b2[nb + ni * 16 + lr];
        #pragma unroll
        for (int mi = 0; mi < 4; ++mi)
            #pragma unroll
            for (int ni = 0; ni < 4; ++ni)
                #pragma unroll
                for (int r = 0; r < 4; ++r)
                    h_lds[(mi * 16 + rbase + r) * HLD + nb + ni * 16 + lr] =
                        f2bf(fmaxf(acc2[mi][ni][r] + bn2[ni], 0.f));
    }
    __syncthreads();
    if (tid < 192) {
        const int pp = tid / 3;
        const int cc = tid - 3 * pp;
        float s = w3_lds[768 + cc];
        #pragma unroll 8
        for (int k = 0; k < 256; ++k)
            s = fmaf(bf2f(h_lds[pp * HLD + k]), w3_lds[k * 3 + cc], s);
        out[(size_t)(blockIdx.x * 64 + pp) * 3 + cc] = 1.f / (1.f + expf(-s));
    }
}

extern "C" void kernel_launch(void* const* d_in, const int* in_sizes, int n_in,
                              void* d_out, int out_size, void* d_ws, size_t ws_size,
                              hipStream_t stream) {
    const float* coords = (const float*)d_in[0];
    const float* stab   = (const float*)d_in[1];
    const float* ttab   = (const float*)d_in[2];
    const float* W1     = (const float*)d_in[3];
    const float* b1     = (const float*)d_in[4];
    const float* W2     = (const float*)d_in[5];
    const float* b2     = (const float*)d_in[6];
    const float* W3     = (const float*)d_in[7];
    const float* b3     = (const float*)d_in[8];

    const int B = in_sizes[0] / 4;  // 262144
    const size_t FEAT_BYTES = (size_t)B * 256;             // bf16 [B][128]
    const size_t W_BYTES = (96 * 256 + 256 * 256) * 2;     // 180224
    const size_t BAR_BYTES = 8 * 8 * sizeof(unsigned);     // 5 phases used

    if (ws_size >= FEAT_BYTES + W_BYTES + BAR_BYTES) {
        unsigned* feat = (unsigned*)d_ws;                  // [B][64] words
        ushort* Wt1 = (ushort*)((char*)d_ws + FEAT_BYTES);
        ushort* Wt2 = Wt1 + 96 * 256;
        unsigned* bar = (unsigned*)((char*)d_ws + FEAT_BYTES + W_BYTES);

        hipMemsetAsync(bar, 0, BAR_BYTES, stream);
        prep_weights<<<352, 256, 0, stream>>>(W1, W2, Wt1, Wt2);
        encode_phase<<<NBLK, 256, 0, stream>>>(
            (const float4*)coords, stab, ttab, feat, bar);
        mlp_kernel<<<B / 64, 256, 0, stream>>>(feat, Wt1, b1, Wt2, b2, W3, b3,
                                               (float*)d_out);
    } else {
        ushort* Wt1 = (ushort*)d_ws;
        ushort* Wt2 = Wt1 + 96 * 256;
        prep_weights<<<352, 256, 0, stream>>>(W1, W2, Wt1, Wt2);
        fused_ngp_fb<<<B / 64, 256, 0, stream>>>((const float4*)coords, stab, ttab,
                                                 Wt1, b1, Wt2, b2, W3, b3,
                                                 (float*)d_out);
    }
}

// Round 6
// 596.362 us; speedup vs baseline: 5.2526x; 2.1891x over previous
//
#include <hip/hip_runtime.h>

typedef __attribute__((ext_vector_type(8))) short short8;
typedef __attribute__((ext_vector_type(4))) float f32x4;

#define T_SIZE (1u << 22)
#define HMASK 0x3FFFFFu
#define P2H 2654435761u
#define P3H 805459861u
#define FLD 104   // feat LDS row stride (ushorts)
#define HLD 264   // hidden LDS row stride (ushorts)

__constant__ float c_RES[24] = {
    16.f, 24.f, 36.f, 54.f, 81.f, 121.f, 182.f, 273.f, 410.f, 615.f,
    922.f, 1383.f, 2075.f, 3113.f, 4670.f, 7006.f, 10509.f, 15764.f,
    23646.f, 35469.f, 53204.f, 79806.f, 119709.f, 179563.f};

static __device__ __forceinline__ ushort f2bf(float f) {
    union { float f; unsigned u; } v; v.f = f;
    unsigned r = v.u + 0x7FFFu + ((v.u >> 16) & 1u);
    return (ushort)(r >> 16);
}
static __device__ __forceinline__ float bf2f(ushort u) {
    union { unsigned u; float f; } v; v.u = ((unsigned)u) << 16; return v.f;
}

// Transpose + bf16-convert W1 (96x256) and W2 (256x256) into ws: Wt[n][k].
__global__ void prep_weights(const float* __restrict__ W1, const float* __restrict__ W2,
                             ushort* __restrict__ Wt1, ushort* __restrict__ Wt2) {
    int id = blockIdx.x * 256 + threadIdx.x;
    if (id < 96 * 256) {
        int n = id / 96, k = id - n * 96;
        Wt1[id] = f2bf(W1[k * 256 + n]);
    }
    int id2 = id - 96 * 256;
    if (id2 >= 0 && id2 < 256 * 256) {
        int n = id2 >> 8, k = id2 & 255;
        Wt2[id2] = f2bf(W2[k * 256 + n]);
    }
}

// x-corner pair with P1==1 structure: h(x0)=ux^A, h(x1)=(ux+1)^A.
// ux even -> h(x1)=h(x0)^1 -> both entries live in one 16B-aligned float4.
// Load that float4 always; only odd ux needs a second (8B) transaction.
static __device__ __forceinline__ void corner_pair(
    const float2* __restrict__ tl, unsigned ux, bool xodd, unsigned A,
    float wx0, float fx, float wyz, float& f0, float& f1) {
    const unsigned h0 = (ux ^ A) & HMASK;
    const float4 pr = *(const float4*)(tl + (h0 & ~1u));
    const bool ho = (h0 & 1u) != 0u;
    const float a0 = ho ? pr.z : pr.x;   // e(x0)
    const float a1 = ho ? pr.w : pr.y;
    float b0, b1;                        // e(x1)
    if (xodd) {
        const unsigned h1 = ((ux + 1u) ^ A) & HMASK;
        const float2 e = tl[h1];
        b0 = e.x; b1 = e.y;
    } else {
        b0 = ho ? pr.x : pr.z;
        b1 = ho ? pr.y : pr.w;
    }
    f0 = fmaf(wyz, fmaf(wx0, a0, fx * b0), f0);
    f1 = fmaf(wyz, fmaf(wx0, a1, fx * b1), f1);
}

// ---------------- fused: encode (paired loads) + MFMA MLP ------------------
__global__ __launch_bounds__(256) void fused_ngp(
    const float4* __restrict__ coords, const float* __restrict__ stab,
    const float* __restrict__ ttab, const ushort* __restrict__ Wt1,
    const float* __restrict__ b1, const ushort* __restrict__ Wt2,
    const float* __restrict__ b2, const float* __restrict__ W3,
    const float* __restrict__ b3, float* __restrict__ out) {
    __shared__ ushort feat_lds[64 * FLD];
    __shared__ ushort h_lds[64 * HLD];
    __shared__ float w3_lds[772];
    const int tid = threadIdx.x;
    for (int i = tid; i < 768; i += 256) w3_lds[i] = W3[i];
    if (tid < 3) w3_lds[768 + tid] = b3[tid];

    // encode: 64 points x 24 levels; 4 threads/point (6 levels each)
    const int p = tid & 63;
    const int g = tid >> 6;
    const float4 c = coords[blockIdx.x * 64 + p];
    #pragma unroll
    for (int dl = 0; dl < 6; ++dl) {
        const int l = g * 6 + dl;
        const float R = c_RES[l];
        float sx = c.x * R, sy = c.y * R, sz = c.z * R;
        float bx = floorf(sx), by = floorf(sy), bz = floorf(sz);
        float fx = sx - bx, fy = sy - by, fz = sz - bz;
        unsigned ux = (unsigned)(int)bx, uy = (unsigned)(int)by, uz = (unsigned)(int)bz;
        unsigned hy0 = uy * P2H, hy1 = hy0 + P2H;
        unsigned hz0 = uz * P3H, hz1 = hz0 + P3H;
        const float2* tl = (const float2*)stab + (size_t)l * T_SIZE;
        const bool xodd = (ux & 1u) != 0u;
        float wx0 = 1.f - fx, wy0 = 1.f - fy, wz0 = 1.f - fz;
        float f0 = 0.f, f1 = 0.f;
        corner_pair(tl, ux, xodd, hy0 ^ hz0, wx0, fx, wy0 * wz0, f0, f1);
        corner_pair(tl, ux, xodd, hy0 ^ hz1, wx0, fx, wy0 * fz,  f0, f1);
        corner_pair(tl, ux, xodd, hy1 ^ hz0, wx0, fx, fy * wz0,  f0, f1);
        corner_pair(tl, ux, xodd, hy1 ^ hz1, wx0, fx, fy * fz,   f0, f1);
        feat_lds[p * FLD + 2 * l]     = f2bf(f0);
        feat_lds[p * FLD + 2 * l + 1] = f2bf(f1);

        // temporal
        float stv = c.w * R;
        float btf = floorf(stv);
        float ftv = stv - btf;
        unsigned utv = (unsigned)(int)btf;
        const float2* ttl = (const float2*)ttab + (size_t)l * T_SIZE;
        float2 e0 = ttl[(utv * P2H) & HMASK], e1 = ttl[((utv + 1u) * P2H) & HMASK];
        feat_lds[p * FLD + 48 + 2 * l]     = f2bf((1.f - ftv) * e0.x + ftv * e1.x);
        feat_lds[p * FLD + 48 + 2 * l + 1] = f2bf((1.f - ftv) * e0.y + ftv * e1.y);
    }
    __syncthreads();

    // ----- layer 1: (64x96)@(96x256)
    const int lane = tid & 63;
    const int wv = tid >> 6;
    const int lr = lane & 15;
    const int lk = (lane >> 4) * 8;
    const int nb = wv * 64;
    const int rbase = (lane >> 4) * 4;
    f32x4 acc[4][4] = {};
    #pragma unroll
    for (int ks = 0; ks < 3; ++ks) {
        short8 a[4], b[4];
        #pragma unroll
        for (int mi = 0; mi < 4; ++mi)
            a[mi] = *(const short8*)&feat_lds[(mi * 16 + lr) * FLD + ks * 32 + lk];
        #pragma unroll
        for (int ni = 0; ni < 4; ++ni)
            b[ni] = *(const short8*)&Wt1[(size_t)(nb + ni * 16 + lr) * 96 + ks * 32 + lk];
        #pragma unroll
        for (int mi = 0; mi < 4; ++mi)
            #pragma unroll
            for (int ni = 0; ni < 4; ++ni)
                acc[mi][ni] = __builtin_amdgcn_mfma_f32_16x16x32_bf16(a[mi], b[ni], acc[mi][ni], 0, 0, 0);
    }
    {
        float bn[4];
        #pragma unroll
        for (int ni = 0; ni < 4; ++ni) bn[ni] = b1[nb + ni * 16 + lr];
        #pragma unroll
        for (int mi = 0; mi < 4; ++mi)
            #pragma unroll
            for (int ni = 0; ni < 4; ++ni)
                #pragma unroll
                for (int r = 0; r < 4; ++r)
                    h_lds[(mi * 16 + rbase + r) * HLD + nb + ni * 16 + lr] =
                        f2bf(fmaxf(acc[mi][ni][r] + bn[ni], 0.f));
    }
    __syncthreads();

    // ----- layer 2: (64x256)@(256x256)
    f32x4 acc2[4][4] = {};
    #pragma unroll
    for (int ks = 0; ks < 8; ++ks) {
        short8 a[4], b[4];
        #pragma unroll
        for (int mi = 0; mi < 4; ++mi)
            a[mi] = *(const short8*)&h_lds[(mi * 16 + lr) * HLD + ks * 32 + lk];
        #pragma unroll
        for (int ni = 0; ni < 4; ++ni)
            b[ni] = *(const short8*)&Wt2[(size_t)(nb + ni * 16 + lr) * 256 + ks * 32 + lk];
        #pragma unroll
        for (int mi = 0; mi < 4; ++mi)
            #pragma unroll
            for (int ni = 0; ni < 4; ++ni)
                acc2[mi][ni] = __builtin_amdgcn_mfma_f32_16x16x32_bf16(a[mi], b[ni], acc2[mi][ni], 0, 0, 0);
    }
    __syncthreads();
    {
        float bn2[4];
        #pragma unroll
        for (int ni = 0; ni < 4; ++ni) bn2[ni] = b2[nb + ni * 16 + lr];
        #pragma unroll
        for (int mi = 0; mi < 4; ++mi)
            #pragma unroll
            for (int ni = 0; ni < 4; ++ni)
                #pragma unroll
                for (int r = 0; r < 4; ++r)
                    h_lds[(mi * 16 + rbase + r) * HLD + nb + ni * 16 + lr] =
                        f2bf(fmaxf(acc2[mi][ni][r] + bn2[ni], 0.f));
    }
    __syncthreads();

    // ----- layer 3 + sigmoid
    if (tid < 192) {
        const int pp = tid / 3;
        const int cc = tid - 3 * pp;
        float s = w3_lds[768 + cc];
        #pragma unroll 8
        for (int k = 0; k < 256; ++k)
            s = fmaf(bf2f(h_lds[pp * HLD + k]), w3_lds[k * 3 + cc], s);
        out[(size_t)(blockIdx.x * 64 + pp) * 3 + cc] = 1.f / (1.f + expf(-s));
    }
}

extern "C" void kernel_launch(void* const* d_in, const int* in_sizes, int n_in,
                              void* d_out, int out_size, void* d_ws, size_t ws_size,
                              hipStream_t stream) {
    const float* coords = (const float*)d_in[0];
    const float* stab   = (const float*)d_in[1];
    const float* ttab   = (const float*)d_in[2];
    const float* W1     = (const float*)d_in[3];
    const float* b1     = (const float*)d_in[4];
    const float* W2     = (const float*)d_in[5];
    const float* b2     = (const float*)d_in[6];
    const float* W3     = (const float*)d_in[7];
    const float* b3     = (const float*)d_in[8];

    ushort* Wt1 = (ushort*)d_ws;            // 96*256 bf16
    ushort* Wt2 = Wt1 + 96 * 256;           // 256*256 bf16

    prep_weights<<<352, 256, 0, stream>>>(W1, W2, Wt1, Wt2);

    const int B = in_sizes[0] / 4;          // 262144
    fused_ngp<<<B / 64, 256, 0, stream>>>((const float4*)coords, stab, ttab,
                                          Wt1, b1, Wt2, b2, W3, b3, (float*)d_out);
}

// Round 7
// 566.864 us; speedup vs baseline: 5.5259x; 1.0520x over previous
//
#include <hip/hip_runtime.h>

typedef __attribute__((ext_vector_type(8))) short short8;
typedef __attribute__((ext_vector_type(4))) float f32x4;

#define T_SIZE (1u << 22)
#define HMASK 0x3FFFFFu
#define P2H 2654435761u
#define P3H 805459861u
#define FLD 104   // feat LDS row stride (ushorts)
#define HLD 264   // hidden LDS row stride (ushorts)

__constant__ float c_RES[24] = {
    16.f, 24.f, 36.f, 54.f, 81.f, 121.f, 182.f, 273.f, 410.f, 615.f,
    922.f, 1383.f, 2075.f, 3113.f, 4670.f, 7006.f, 10509.f, 15764.f,
    23646.f, 35469.f, 53204.f, 79806.f, 119709.f, 179563.f};

static __device__ __forceinline__ ushort f2bf(float f) {
    union { float f; unsigned u; } v; v.f = f;
    unsigned r = v.u + 0x7FFFu + ((v.u >> 16) & 1u);
    return (ushort)(r >> 16);
}
static __device__ __forceinline__ float bf2f(ushort u) {
    union { unsigned u; float f; } v; v.u = ((unsigned)u) << 16; return v.f;
}

// Transpose + bf16-convert W1 (96x256) and W2 (256x256) into ws: Wt[n][k].
__global__ void prep_weights(const float* __restrict__ W1, const float* __restrict__ W2,
                             ushort* __restrict__ Wt1, ushort* __restrict__ Wt2) {
    int id = blockIdx.x * 256 + threadIdx.x;
    if (id < 96 * 256) {
        int n = id / 96, k = id - n * 96;
        Wt1[id] = f2bf(W1[k * 256 + n]);
    }
    int id2 = id - 96 * 256;
    if (id2 >= 0 && id2 < 256 * 256) {
        int n = id2 >> 8, k = id2 & 255;
        Wt2[id2] = f2bf(W2[k * 256 + n]);
    }
}

// x-corner pair with P1==1 structure: h(x0)=ux^A, h(x1)=(ux+1)^A.
// ux even -> h(x1)=h(x0)^1 -> both entries live in one 16B-aligned float4.
// Load that float4 always; only odd ux needs a second (8B) transaction.
static __device__ __forceinline__ void corner_pair(
    const float2* __restrict__ tl, unsigned ux, bool xodd, unsigned A,
    float wx0, float fx, float wyz, float& f0, float& f1) {
    const unsigned h0 = (ux ^ A) & HMASK;
    const float4 pr = *(const float4*)(tl + (h0 & ~1u));
    const bool ho = (h0 & 1u) != 0u;
    const float a0 = ho ? pr.z : pr.x;   // e(x0)
    const float a1 = ho ? pr.w : pr.y;
    float b0, b1;                        // e(x1)
    if (xodd) {
        const unsigned h1 = ((ux + 1u) ^ A) & HMASK;
        const float2 e = tl[h1];
        b0 = e.x; b1 = e.y;
    } else {
        b0 = ho ? pr.x : pr.z;
        b1 = ho ? pr.y : pr.w;
    }
    f0 = fmaf(wyz, fmaf(wx0, a0, fx * b0), f0);
    f1 = fmaf(wyz, fmaf(wx0, a1, fx * b1), f1);
}

// ---------------- fused: encode (paired loads) + MFMA MLP ------------------
// 512 threads / 64 points per block: 8 threads/point (3 levels each) during
// encode -> 24 gather-issuing waves/CU (3 blocks x 8 waves) vs 12 before.
// MLP: 8 waves, wave wv owns 32 N-cols.
__global__ __launch_bounds__(512, 6) void fused_ngp(
    const float4* __restrict__ coords, const float* __restrict__ stab,
    const float* __restrict__ ttab, const ushort* __restrict__ Wt1,
    const float* __restrict__ b1, const ushort* __restrict__ Wt2,
    const float* __restrict__ b2, const float* __restrict__ W3,
    const float* __restrict__ b3, float* __restrict__ out) {
    __shared__ ushort feat_lds[64 * FLD];
    __shared__ ushort h_lds[64 * HLD];
    __shared__ float w3_lds[772];
    const int tid = threadIdx.x;
    for (int i = tid; i < 768; i += 512) w3_lds[i] = W3[i];
    if (tid < 3) w3_lds[768 + tid] = b3[tid];

    // encode: 64 points x 24 levels; 8 threads/point, 3 levels each
    const int p = tid & 63;
    const int g = tid >> 6;   // 0..7
    const float4 c = coords[blockIdx.x * 64 + p];
    #pragma unroll
    for (int dl = 0; dl < 3; ++dl) {
        const int l = g * 3 + dl;
        const float R = c_RES[l];
        float sx = c.x * R, sy = c.y * R, sz = c.z * R;
        float bx = floorf(sx), by = floorf(sy), bz = floorf(sz);
        float fx = sx - bx, fy = sy - by, fz = sz - bz;
        unsigned ux = (unsigned)(int)bx, uy = (unsigned)(int)by, uz = (unsigned)(int)bz;
        unsigned hy0 = uy * P2H, hy1 = hy0 + P2H;
        unsigned hz0 = uz * P3H, hz1 = hz0 + P3H;
        const float2* tl = (const float2*)stab + (size_t)l * T_SIZE;
        const bool xodd = (ux & 1u) != 0u;
        float wx0 = 1.f - fx, wy0 = 1.f - fy, wz0 = 1.f - fz;
        float f0 = 0.f, f1 = 0.f;
        corner_pair(tl, ux, xodd, hy0 ^ hz0, wx0, fx, wy0 * wz0, f0, f1);
        corner_pair(tl, ux, xodd, hy0 ^ hz1, wx0, fx, wy0 * fz,  f0, f1);
        corner_pair(tl, ux, xodd, hy1 ^ hz0, wx0, fx, fy * wz0,  f0, f1);
        corner_pair(tl, ux, xodd, hy1 ^ hz1, wx0, fx, fy * fz,   f0, f1);
        feat_lds[p * FLD + 2 * l]     = f2bf(f0);
        feat_lds[p * FLD + 2 * l + 1] = f2bf(f1);

        // temporal
        float stv = c.w * R;
        float btf = floorf(stv);
        float ftv = stv - btf;
        unsigned utv = (unsigned)(int)btf;
        const float2* ttl = (const float2*)ttab + (size_t)l * T_SIZE;
        float2 e0 = ttl[(utv * P2H) & HMASK], e1 = ttl[((utv + 1u) * P2H) & HMASK];
        feat_lds[p * FLD + 48 + 2 * l]     = f2bf((1.f - ftv) * e0.x + ftv * e1.x);
        feat_lds[p * FLD + 48 + 2 * l + 1] = f2bf((1.f - ftv) * e0.y + ftv * e1.y);
    }
    __syncthreads();

    // ----- layer 1: (64x96)@(96x256); wave wv owns N cols [wv*32, wv*32+32)
    const int lane = tid & 63;
    const int wv = tid >> 6;
    const int lr = lane & 15;
    const int lk = (lane >> 4) * 8;
    const int nb = wv * 32;
    const int rbase = (lane >> 4) * 4;
    f32x4 acc[4][2] = {};
    #pragma unroll
    for (int ks = 0; ks < 3; ++ks) {
        short8 a[4], b[2];
        #pragma unroll
        for (int mi = 0; mi < 4; ++mi)
            a[mi] = *(const short8*)&feat_lds[(mi * 16 + lr) * FLD + ks * 32 + lk];
        #pragma unroll
        for (int ni = 0; ni < 2; ++ni)
            b[ni] = *(const short8*)&Wt1[(size_t)(nb + ni * 16 + lr) * 96 + ks * 32 + lk];
        #pragma unroll
        for (int mi = 0; mi < 4; ++mi)
            #pragma unroll
            for (int ni = 0; ni < 2; ++ni)
                acc[mi][ni] = __builtin_amdgcn_mfma_f32_16x16x32_bf16(a[mi], b[ni], acc[mi][ni], 0, 0, 0);
    }
    {
        float bn[2];
        #pragma unroll
        for (int ni = 0; ni < 2; ++ni) bn[ni] = b1[nb + ni * 16 + lr];
        #pragma unroll
        for (int mi = 0; mi < 4; ++mi)
            #pragma unroll
            for (int ni = 0; ni < 2; ++ni)
                #pragma unroll
                for (int r = 0; r < 4; ++r)
                    h_lds[(mi * 16 + rbase + r) * HLD + nb + ni * 16 + lr] =
                        f2bf(fmaxf(acc[mi][ni][r] + bn[ni], 0.f));
    }
    __syncthreads();

    // ----- layer 2: (64x256)@(256x256)
    f32x4 acc2[4][2] = {};
    #pragma unroll
    for (int ks = 0; ks < 8; ++ks) {
        short8 a[4], b[2];
        #pragma unroll
        for (int mi = 0; mi < 4; ++mi)
            a[mi] = *(const short8*)&h_lds[(mi * 16 + lr) * HLD + ks * 32 + lk];
        #pragma unroll
        for (int ni = 0; ni < 2; ++ni)
            b[ni] = *(const short8*)&Wt2[(size_t)(nb + ni * 16 + lr) * 256 + ks * 32 + lk];
        #pragma unroll
        for (int mi = 0; mi < 4; ++mi)
            #pragma unroll
            for (int ni = 0; ni < 2; ++ni)
                acc2[mi][ni] = __builtin_amdgcn_mfma_f32_16x16x32_bf16(a[mi], b[ni], acc2[mi][ni], 0, 0, 0);
    }
    __syncthreads();
    {
        float bn2[2];
        #pragma unroll
        for (int ni = 0; ni < 2; ++ni) bn2[ni] = b2[nb + ni * 16 + lr];
        #pragma unroll
        for (int mi = 0; mi < 4; ++mi)
            #pragma unroll
            for (int ni = 0; ni < 2; ++ni)
                #pragma unroll
                for (int r = 0; r < 4; ++r)
                    h_lds[(mi * 16 + rbase + r) * HLD + nb + ni * 16 + lr] =
                        f2bf(fmaxf(acc2[mi][ni][r] + bn2[ni], 0.f));
    }
    __syncthreads();

    // ----- layer 3 + sigmoid
    if (tid < 192) {
        const int pp = tid / 3;
        const int cc = tid - 3 * pp;
        float s = w3_lds[768 + cc];
        #pragma unroll 8
        for (int k = 0; k < 256; ++k)
            s = fmaf(bf2f(h_lds[pp * HLD + k]), w3_lds[k * 3 + cc], s);
        out[(size_t)(blockIdx.x * 64 + pp) * 3 + cc] = 1.f / (1.f + expf(-s));
    }
}

extern "C" void kernel_launch(void* const* d_in, const int* in_sizes, int n_in,
                              void* d_out, int out_size, void* d_ws, size_t ws_size,
                              hipStream_t stream) {
    const float* coords = (const float*)d_in[0];
    const float* stab   = (const float*)d_in[1];
    const float* ttab   = (const float*)d_in[2];
    const float* W1     = (const float*)d_in[3];
    const float* b1     = (const float*)d_in[4];
    const float* W2     = (const float*)d_in[5];
    const float* b2     = (const float*)d_in[6];
    const float* W3     = (const float*)d_in[7];
    const float* b3     = (const float*)d_in[8];

    ushort* Wt1 = (ushort*)d_ws;            // 96*256 bf16
    ushort* Wt2 = Wt1 + 96 * 256;           // 256*256 bf16

    prep_weights<<<352, 256, 0, stream>>>(W1, W2, Wt1, Wt2);

    const int B = in_sizes[0] / 4;          // 262144
    fused_ngp<<<B / 64, 512, 0, stream>>>((const float4*)coords, stab, ttab,
                                          Wt1, b1, Wt2, b2, W3, b3, (float*)d_out);
}

// Round 8
// 507.578 us; speedup vs baseline: 6.1714x; 1.1168x over previous
//
#include <hip/hip_runtime.h>

typedef __attribute__((ext_vector_type(8))) short short8;
typedef __attribute__((ext_vector_type(4))) float f32x4;

#define T_SIZE (1u << 22)
#define HMASK 0x3FFFFFu
#define P2H 2654435761u
#define P3H 805459861u
#define FLD 104   // feat LDS row stride (ushorts)
#define HLD 264   // hidden LDS row stride (ushorts)
#define TLUT_N 538675u

__constant__ float c_RES[24] = {
    16.f, 24.f, 36.f, 54.f, 81.f, 121.f, 182.f, 273.f, 410.f, 615.f,
    922.f, 1383.f, 2075.f, 3113.f, 4670.f, 7006.f, 10509.f, 15764.f,
    23646.f, 35469.f, 53204.f, 79806.f, 119709.f, 179563.f};

// c_TOFF[l] = sum_{i<l} (RES[i]+1); temporal LUT level offsets
__constant__ unsigned c_TOFF[25] = {
    0, 17, 42, 79, 134, 216, 338, 521, 795, 1206, 1822, 2745, 4129, 6205,
    9319, 13990, 20997, 31507, 47272, 70919, 106389, 159594, 239401, 359111,
    538675};

static __device__ __forceinline__ ushort f2bf(float f) {
    union { float f; unsigned u; } v; v.f = f;
    unsigned r = v.u + 0x7FFFu + ((v.u >> 16) & 1u);
    return (ushort)(r >> 16);
}
static __device__ __forceinline__ float bf2f(ushort u) {
    union { unsigned u; float f; } v; v.u = ((unsigned)u) << 16; return v.f;
}

// Transpose + bf16-convert W1 (96x256) and W2 (256x256) into ws: Wt[n][k].
__global__ void prep_weights(const float* __restrict__ W1, const float* __restrict__ W2,
                             ushort* __restrict__ Wt1, ushort* __restrict__ Wt2) {
    int id = blockIdx.x * 256 + threadIdx.x;
    if (id < 96 * 256) {
        int n = id / 96, k = id - n * 96;
        Wt1[id] = f2bf(W1[k * 256 + n]);
    }
    int id2 = id - 96 * 256;
    if (id2 >= 0 && id2 < 256 * 256) {
        int n = id2 >> 8, k = id2 & 255;
        Wt2[id2] = f2bf(W2[k * 256 + n]);
    }
}

// Densify the temporal table: only entries h(j)=j*P2H&MASK, j in [0,RES_l],
// are ever touched -> build dense D[off_l + j] (4.3MB, cache-resident).
__global__ void build_tlut(const float2* __restrict__ ttab, float2* __restrict__ D) {
    const unsigned id = blockIdx.x * 256u + threadIdx.x;
    if (id >= TLUT_N) return;
    int l = 0;
    #pragma unroll
    for (int i = 1; i < 24; ++i) l += (id >= c_TOFF[i]);
    const unsigned j = id - c_TOFF[l];
    D[id] = ttab[((size_t)l << 22) + ((j * P2H) & HMASK)];
}

// x-corner pair with P1==1 structure: h(x0)=ux^A, h(x1)=(ux+1)^A.
// ux even -> h(x1)=h(x0)^1 -> both entries live in one 16B-aligned float4.
// Load that float4 always; only odd ux needs a second (8B) transaction.
static __device__ __forceinline__ void corner_pair(
    const float2* __restrict__ tl, unsigned ux, bool xodd, unsigned A,
    float wx0, float fx, float wyz, float& f0, float& f1) {
    const unsigned h0 = (ux ^ A) & HMASK;
    const float4 pr = *(const float4*)(tl + (h0 & ~1u));
    const bool ho = (h0 & 1u) != 0u;
    const float a0 = ho ? pr.z : pr.x;   // e(x0)
    const float a1 = ho ? pr.w : pr.y;
    float b0, b1;                        // e(x1)
    if (xodd) {
        const unsigned h1 = ((ux + 1u) ^ A) & HMASK;
        const float2 e = tl[h1];
        b0 = e.x; b1 = e.y;
    } else {
        b0 = ho ? pr.x : pr.z;
        b1 = ho ? pr.y : pr.w;
    }
    f0 = fmaf(wyz, fmaf(wx0, a0, fx * b0), f0);
    f1 = fmaf(wyz, fmaf(wx0, a1, fx * b1), f1);
}

// ---------------- fused: encode (paired loads + temporal LUT) + MFMA MLP ---
// 512 threads / 64 points per block: 8 threads/point (3 levels each).
__global__ __launch_bounds__(512, 6) void fused_ngp(
    const float4* __restrict__ coords, const float* __restrict__ stab,
    const float2* __restrict__ tlut, const ushort* __restrict__ Wt1,
    const float* __restrict__ b1, const ushort* __restrict__ Wt2,
    const float* __restrict__ b2, const float* __restrict__ W3,
    const float* __restrict__ b3, float* __restrict__ out) {
    __shared__ ushort feat_lds[64 * FLD];
    __shared__ ushort h_lds[64 * HLD];
    __shared__ float w3_lds[772];
    const int tid = threadIdx.x;
    for (int i = tid; i < 768; i += 512) w3_lds[i] = W3[i];
    if (tid < 3) w3_lds[768 + tid] = b3[tid];

    // encode: 64 points x 24 levels; 8 threads/point, 3 levels each
    const int p = tid & 63;
    const int g = tid >> 6;   // 0..7
    const float4 c = coords[blockIdx.x * 64 + p];
    #pragma unroll
    for (int dl = 0; dl < 3; ++dl) {
        const int l = g * 3 + dl;
        const float R = c_RES[l];
        float sx = c.x * R, sy = c.y * R, sz = c.z * R;
        float bx = floorf(sx), by = floorf(sy), bz = floorf(sz);
        float fx = sx - bx, fy = sy - by, fz = sz - bz;
        unsigned ux = (unsigned)(int)bx, uy = (unsigned)(int)by, uz = (unsigned)(int)bz;
        unsigned hy0 = uy * P2H, hy1 = hy0 + P2H;
        unsigned hz0 = uz * P3H, hz1 = hz0 + P3H;
        const float2* tl = (const float2*)stab + (size_t)l * T_SIZE;
        const bool xodd = (ux & 1u) != 0u;
        float wx0 = 1.f - fx, wy0 = 1.f - fy, wz0 = 1.f - fz;
        float f0 = 0.f, f1 = 0.f;
        corner_pair(tl, ux, xodd, hy0 ^ hz0, wx0, fx, wy0 * wz0, f0, f1);
        corner_pair(tl, ux, xodd, hy0 ^ hz1, wx0, fx, wy0 * fz,  f0, f1);
        corner_pair(tl, ux, xodd, hy1 ^ hz0, wx0, fx, fy * wz0,  f0, f1);
        corner_pair(tl, ux, xodd, hy1 ^ hz1, wx0, fx, fy * fz,   f0, f1);
        feat_lds[p * FLD + 2 * l]     = f2bf(f0);
        feat_lds[p * FLD + 2 * l + 1] = f2bf(f1);

        // temporal via dense LUT (cache-resident)
        float stv = c.w * R;
        float btf = floorf(stv);
        float ftv = stv - btf;
        unsigned utv = (unsigned)(int)btf;
        const float2* Dl = tlut + c_TOFF[l];
        float2 e0 = Dl[utv], e1 = Dl[utv + 1u];
        feat_lds[p * FLD + 48 + 2 * l]     = f2bf((1.f - ftv) * e0.x + ftv * e1.x);
        feat_lds[p * FLD + 48 + 2 * l + 1] = f2bf((1.f - ftv) * e0.y + ftv * e1.y);
    }
    __syncthreads();

    // ----- layer 1: (64x96)@(96x256); wave wv owns N cols [wv*32, wv*32+32)
    const int lane = tid & 63;
    const int wv = tid >> 6;
    const int lr = lane & 15;
    const int lk = (lane >> 4) * 8;
    const int nb = wv * 32;
    const int rbase = (lane >> 4) * 4;
    f32x4 acc[4][2] = {};
    #pragma unroll
    for (int ks = 0; ks < 3; ++ks) {
        short8 a[4], b[2];
        #pragma unroll
        for (int mi = 0; mi < 4; ++mi)
            a[mi] = *(const short8*)&feat_lds[(mi * 16 + lr) * FLD + ks * 32 + lk];
        #pragma unroll
        for (int ni = 0; ni < 2; ++ni)
            b[ni] = *(const short8*)&Wt1[(size_t)(nb + ni * 16 + lr) * 96 + ks * 32 + lk];
        #pragma unroll
        for (int mi = 0; mi < 4; ++mi)
            #pragma unroll
            for (int ni = 0; ni < 2; ++ni)
                acc[mi][ni] = __builtin_amdgcn_mfma_f32_16x16x32_bf16(a[mi], b[ni], acc[mi][ni], 0, 0, 0);
    }
    {
        float bn[2];
        #pragma unroll
        for (int ni = 0; ni < 2; ++ni) bn[ni] = b1[nb + ni * 16 + lr];
        #pragma unroll
        for (int mi = 0; mi < 4; ++mi)
            #pragma unroll
            for (int ni = 0; ni < 2; ++ni)
                #pragma unroll
                for (int r = 0; r < 4; ++r)
                    h_lds[(mi * 16 + rbase + r) * HLD + nb + ni * 16 + lr] =
                        f2bf(fmaxf(acc[mi][ni][r] + bn[ni], 0.f));
    }
    __syncthreads();

    // ----- layer 2: (64x256)@(256x256)
    f32x4 acc2[4][2] = {};
    #pragma unroll
    for (int ks = 0; ks < 8; ++ks) {
        short8 a[4], b[2];
        #pragma unroll
        for (int mi = 0; mi < 4; ++mi)
            a[mi] = *(const short8*)&h_lds[(mi * 16 + lr) * HLD + ks * 32 + lk];
        #pragma unroll
        for (int ni = 0; ni < 2; ++ni)
            b[ni] = *(const short8*)&Wt2[(size_t)(nb + ni * 16 + lr) * 256 + ks * 32 + lk];
        #pragma unroll
        for (int mi = 0; mi < 4; ++mi)
            #pragma unroll
            for (int ni = 0; ni < 2; ++ni)
                acc2[mi][ni] = __builtin_amdgcn_mfma_f32_16x16x32_bf16(a[mi], b[ni], acc2[mi][ni], 0, 0, 0);
    }
    __syncthreads();
    {
        float bn2[2];
        #pragma unroll
        for (int ni = 0; ni < 2; ++ni) bn2[ni] = b2[nb + ni * 16 + lr];
        #pragma unroll
        for (int mi = 0; mi < 4; ++mi)
            #pragma unroll
            for (int ni = 0; ni < 2; ++ni)
                #pragma unroll
                for (int r = 0; r < 4; ++r)
                    h_lds[(mi * 16 + rbase + r) * HLD + nb + ni * 16 + lr] =
                        f2bf(fmaxf(acc2[mi][ni][r] + bn2[ni], 0.f));
    }
    __syncthreads();

    // ----- layer 3 + sigmoid
    if (tid < 192) {
        const int pp = tid / 3;
        const int cc = tid - 3 * pp;
        float s = w3_lds[768 + cc];
        #pragma unroll 8
        for (int k = 0; k < 256; ++k)
            s = fmaf(bf2f(h_lds[pp * HLD + k]), w3_lds[k * 3 + cc], s);
        out[(size_t)(blockIdx.x * 64 + pp) * 3 + cc] = 1.f / (1.f + expf(-s));
    }
}

extern "C" void kernel_launch(void* const* d_in, const int* in_sizes, int n_in,
                              void* d_out, int out_size, void* d_ws, size_t ws_size,
                              hipStream_t stream) {
    const float* coords = (const float*)d_in[0];
    const float* stab   = (const float*)d_in[1];
    const float* ttab   = (const float*)d_in[2];
    const float* W1     = (const float*)d_in[3];
    const float* b1     = (const float*)d_in[4];
    const float* W2     = (const float*)d_in[5];
    const float* b2     = (const float*)d_in[6];
    const float* W3     = (const float*)d_in[7];
    const float* b3     = (const float*)d_in[8];

    ushort* Wt1 = (ushort*)d_ws;                      // 96*256 bf16
    ushort* Wt2 = Wt1 + 96 * 256;                     // 256*256 bf16
    float2* tlut = (float2*)(Wt2 + 256 * 256);        // 538675 float2 (4.3MB)

    prep_weights<<<352, 256, 0, stream>>>(W1, W2, Wt1, Wt2);
    build_tlut<<<(TLUT_N + 255) / 256, 256, 0, stream>>>((const float2*)ttab, tlut);

    const int B = in_sizes[0] / 4;                    // 262144
    fused_ngp<<<B / 64, 512, 0, stream>>>((const float4*)coords, stab, tlut,
                                          Wt1, b1, Wt2, b2, W3, b3, (float*)d_out);
}